// Round 5
// baseline (367.920 us; speedup 1.0000x reference)
//
#include <hip/hip_runtime.h>
#include <hip/hip_bf16.h>

// N=50000 nodes, IN=256, H=8 heads, D=32, HD=256, E=800000 edges (from in_sizes).

typedef __attribute__((ext_vector_type(8))) short short8;
typedef __attribute__((ext_vector_type(8))) unsigned short ushortx8;
typedef __attribute__((ext_vector_type(4))) unsigned short ushortx4;
typedef __attribute__((ext_vector_type(4))) float floatx4;
typedef __attribute__((ext_vector_type(4))) int intx4;

__device__ __forceinline__ void g2l16(const void* g, void* l) {
    __builtin_amdgcn_global_load_lds(
        (const __attribute__((address_space(1))) unsigned int*)g,
        (__attribute__((address_space(3))) unsigned int*)l, 16, 0, 0);
}

__device__ __forceinline__ float bf2f(unsigned short u) {
    union { unsigned int i; float f; } c; c.i = ((unsigned int)u) << 16; return c.f;
}
__device__ __forceinline__ unsigned short f2bf(float f) {
    __hip_bfloat16 b = __float2bfloat16(f);
    return *reinterpret_cast<unsigned short*>(&b);
}

__device__ __forceinline__ ushortx4 cvt4(floatx4 f) {
    ushortx4 u;
    u.x = f2bf(f.x); u.y = f2bf(f.y); u.z = f2bf(f.z); u.w = f2bf(f.w);
    return u;
}

// ---- fused prep: h->bf16, W->bf16, degree count ----
#define PREP_BH 1563   // h: 3.2M floatx4 / (1563*256) ~ 8 iters/thread
#define PREP_BW 16     // per W matrix: 16384 floatx4 / (16*256) = 4 iters/thread
#define PREP_BD 256    // deg: 200K intx4 / (256*256) ~ 3 iters/thread

__global__ __launch_bounds__(256) void prep(
    const float* __restrict__ h, unsigned short* __restrict__ hb,
    const float* __restrict__ Wq, const float* __restrict__ Wk, const float* __restrict__ Wv,
    unsigned short* __restrict__ Wb,
    const int* __restrict__ dst, int* __restrict__ deg,
    int n4h, int n4w, int E)
{
    const int bid = blockIdx.x;
    const int tid = threadIdx.x;
    if (bid < PREP_BH) {
        const int stride = PREP_BH * 256;
        const floatx4* hs = (const floatx4*)h;
        ushortx4* hd = (ushortx4*)hb;
        int i = bid * 256 + tid;
        // 8-deep batch: 8 loads in flight before any store
        for (; i + 7 * stride < n4h; i += 8 * stride) {
            floatx4 f0 = __builtin_nontemporal_load(hs + i);
            floatx4 f1 = __builtin_nontemporal_load(hs + i + stride);
            floatx4 f2 = __builtin_nontemporal_load(hs + i + 2 * stride);
            floatx4 f3 = __builtin_nontemporal_load(hs + i + 3 * stride);
            floatx4 f4 = __builtin_nontemporal_load(hs + i + 4 * stride);
            floatx4 f5 = __builtin_nontemporal_load(hs + i + 5 * stride);
            floatx4 f6 = __builtin_nontemporal_load(hs + i + 6 * stride);
            floatx4 f7 = __builtin_nontemporal_load(hs + i + 7 * stride);
            hd[i] = cvt4(f0);
            hd[i + stride] = cvt4(f1);
            hd[i + 2 * stride] = cvt4(f2);
            hd[i + 3 * stride] = cvt4(f3);
            hd[i + 4 * stride] = cvt4(f4);
            hd[i + 5 * stride] = cvt4(f5);
            hd[i + 6 * stride] = cvt4(f6);
            hd[i + 7 * stride] = cvt4(f7);
        }
        for (; i < n4h; i += stride) {
            floatx4 f = __builtin_nontemporal_load(hs + i);
            hd[i] = cvt4(f);
        }
    } else if (bid < PREP_BH + 3 * PREP_BW) {
        int b2 = bid - PREP_BH;
        int mat = b2 / PREP_BW;
        const floatx4* ws = (const floatx4*)((mat == 0) ? Wq : (mat == 1) ? Wk : Wv);
        ushortx4* wd = (ushortx4*)(Wb + (size_t)mat * 65536);
        const int stride = PREP_BW * 256;
        int i = (b2 % PREP_BW) * 256 + tid;
        for (; i + 3 * stride < n4w; i += 4 * stride) {
            floatx4 f0 = __builtin_nontemporal_load(ws + i);
            floatx4 f1 = __builtin_nontemporal_load(ws + i + stride);
            floatx4 f2 = __builtin_nontemporal_load(ws + i + 2 * stride);
            floatx4 f3 = __builtin_nontemporal_load(ws + i + 3 * stride);
            wd[i] = cvt4(f0);
            wd[i + stride] = cvt4(f1);
            wd[i + 2 * stride] = cvt4(f2);
            wd[i + 3 * stride] = cvt4(f3);
        }
        for (; i < n4w; i += stride) {
            floatx4 f = __builtin_nontemporal_load(ws + i);
            wd[i] = cvt4(f);
        }
    } else {
        int b3 = bid - PREP_BH - 3 * PREP_BW;
        const int stride = PREP_BD * 256;
        const int ne4 = E >> 2;
        const intx4* ds = (const intx4*)dst;
        int i = b3 * 256 + tid;
        for (; i + stride < ne4; i += 2 * stride) {
            intx4 d0 = __builtin_nontemporal_load(ds + i);
            intx4 d1 = __builtin_nontemporal_load(ds + i + stride);
            atomicAdd(&deg[d0.x], 1); atomicAdd(&deg[d0.y], 1);
            atomicAdd(&deg[d0.z], 1); atomicAdd(&deg[d0.w], 1);
            atomicAdd(&deg[d1.x], 1); atomicAdd(&deg[d1.y], 1);
            atomicAdd(&deg[d1.z], 1); atomicAdd(&deg[d1.w], 1);
        }
        for (; i < ne4; i += stride) {
            intx4 d = __builtin_nontemporal_load(ds + i);
            atomicAdd(&deg[d.x], 1); atomicAdd(&deg[d.y], 1);
            atomicAdd(&deg[d.z], 1); atomicAdd(&deg[d.w], 1);
        }
        if (b3 == 0 && tid == 0) {
            for (int e = ne4 * 4; e < E; e++) atomicAdd(&deg[dst[e]], 1);
        }
    }
}

// ---- bf16 MFMA QKV projection, BK=64 (proven loop) ----
__global__ __launch_bounds__(256) void qkv_gemm_mfma(
    const unsigned short* __restrict__ hb, const unsigned short* __restrict__ Wb,
    const float* __restrict__ bq, const float* __restrict__ bk, const float* __restrict__ bv,
    unsigned short* __restrict__ Qb, unsigned short* __restrict__ KV, int N)
{
    __shared__ unsigned short Ast[2][128 * 32];
    __shared__ unsigned short Bst[2][128 * 32];

    const int tid = threadIdx.x;
    const int wave = tid >> 6;
    const int lane = tid & 63;
    const int m = lane & 15;
    const int q = lane >> 4;
    const int wr = wave >> 1, wc = wave & 1;

    const int nwg = gridDim.x;
    const int orig = blockIdx.x;
    const int q8 = nwg >> 3, r8 = nwg & 7;
    const int xcd = orig & 7;
    const int wgid = (xcd < r8 ? xcd * (q8 + 1) : r8 * (q8 + 1) + (xcd - r8) * q8)
                     + (orig >> 3);
    const int bx = wgid / 6;   // row tile
    const int by = wgid % 6;   // mat/col-half

    const int mbase = bx * 128;
    const int mat = by >> 1;                 // 0:Q 1:K 2:V
    const int colbase = (by & 1) * 128;
    const int wrow0 = by * 128;

    const float* bias = (mat == 0) ? bq : (mat == 1) ? bk : bv;

    floatx4 acc[4][4] = {};

    for (int kk = 0; kk < 256; kk += 64) {
#pragma unroll
        for (int c = 0; c < 2; c++) {
#pragma unroll
            for (int t = 0; t < 2; t++) {
                int f = t * 256 + tid;
                int row = f >> 2, kc = f & 3;
                int grow = mbase + row; if (grow > N - 1) grow = N - 1;
                g2l16(hb + (size_t)grow * 256 + kk + c * 32 + kc * 8,
                      Ast[c] + (size_t)(t * 256 + wave * 64) * 8);
            }
#pragma unroll
            for (int t = 0; t < 2; t++) {
                int f = t * 256 + tid;
                int row = f >> 2, kc = f & 3;
                g2l16(Wb + (size_t)(wrow0 + row) * 256 + kk + c * 32 + kc * 8,
                      Bst[c] + (size_t)(t * 256 + wave * 64) * 8);
            }
        }
        __syncthreads();

#pragma unroll
        for (int c = 0; c < 2; c++) {
            short8 a[4], b[4];
#pragma unroll
            for (int i = 0; i < 4; i++) {
                int r = wr * 64 + i * 16 + m;
                a[i] = *(const short8*)&Ast[c][r * 32 + q * 8];
            }
#pragma unroll
            for (int j = 0; j < 4; j++) {
                int cc = wc * 64 + j * 16 + m;
                b[j] = *(const short8*)&Bst[c][cc * 32 + q * 8];
            }
#pragma unroll
            for (int i = 0; i < 4; i++)
#pragma unroll
                for (int j = 0; j < 4; j++)
                    acc[i][j] = __builtin_amdgcn_mfma_f32_16x16x32_bf16(a[i], b[j], acc[i][j], 0, 0, 0);
        }
        __syncthreads();
    }

    float bvj[4];
#pragma unroll
    for (int j = 0; j < 4; j++) bvj[j] = bias[colbase + wc * 64 + j * 16 + m];

    const int col0 = colbase + wc * 64 + m;
    // C/D layout: col = lane&15, row = (lane>>4)*4 + reg
#pragma unroll
    for (int i = 0; i < 4; i++) {
#pragma unroll
        for (int r = 0; r < 4; r++) {
            int grow = mbase + wr * 64 + i * 16 + q * 4 + r;
            if (grow < N) {
                if (mat == 0) {
                    unsigned short* op = Qb + (size_t)grow * 256 + col0;
#pragma unroll
                    for (int j = 0; j < 4; j++)
                        __builtin_nontemporal_store(f2bf(acc[i][j][r] + bvj[j]), op + j * 16);
                } else {
                    unsigned short* op = KV + (size_t)grow * 512 + ((mat == 2) ? 256 : 0) + col0;
#pragma unroll
                    for (int j = 0; j < 4; j++)
                        op[j * 16] = f2bf(acc[i][j][r] + bvj[j]);
                }
            }
        }
    }
}

#define SCAN_CHUNK 2048  // 256 threads x 8

__global__ void scan_phase1(const int* __restrict__ deg, int* __restrict__ partials, int N) {
    __shared__ int sdata[256];
    int base = blockIdx.x * SCAN_CHUNK;
    int sum = 0;
#pragma unroll
    for (int i = 0; i < 8; i++) {
        int idx = base + threadIdx.x + i * 256;
        if (idx < N) sum += deg[idx];
    }
    sdata[threadIdx.x] = sum;
    __syncthreads();
    for (int s = 128; s > 0; s >>= 1) {
        if (threadIdx.x < (unsigned)s) sdata[threadIdx.x] += sdata[threadIdx.x + s];
        __syncthreads();
    }
    if (threadIdx.x == 0) partials[blockIdx.x] = sdata[0];
}

// scan_phase3 with inlined cross-block prefix: each block wave-reduces the raw
// partials it needs (nb<=64), eliminating the serial single-thread scan_phase2
// kernel (25 dependent global round-trips + a launch).
__global__ void scan_phase3(const int* __restrict__ deg, const int* __restrict__ partials,
                            int* __restrict__ offsets, int* __restrict__ cursor,
                            int N, int E, int nb) {
    __shared__ int sdata[256];
    __shared__ int sbase;
    if (threadIdx.x < 64) {
        int v = ((int)threadIdx.x < nb && (int)threadIdx.x < (int)blockIdx.x)
                    ? partials[threadIdx.x] : 0;
#pragma unroll
        for (int s = 1; s < 64; s <<= 1) v += __shfl_xor(v, s);
        if (threadIdx.x == 0) sbase = v;
    }
    int base = blockIdx.x * SCAN_CHUNK;
    int vals[8];
    int sum = 0;
#pragma unroll
    for (int i = 0; i < 8; i++) {
        int idx = base + threadIdx.x * 8 + i;
        vals[i] = (idx < N) ? deg[idx] : 0;
        sum += vals[i];
    }
    sdata[threadIdx.x] = sum;
    __syncthreads();
    for (int s = 1; s < 256; s <<= 1) {
        int v = sdata[threadIdx.x];
        int add = (threadIdx.x >= (unsigned)s) ? sdata[threadIdx.x - s] : 0;
        __syncthreads();
        sdata[threadIdx.x] = v + add;
        __syncthreads();
    }
    int excl = (threadIdx.x == 0) ? 0 : sdata[threadIdx.x - 1];
    int run = sbase + excl;
#pragma unroll
    for (int i = 0; i < 8; i++) {
        int idx = base + threadIdx.x * 8 + i;
        if (idx < N) { offsets[idx] = run; cursor[idx] = run; }
        run += vals[i];
    }
    if (blockIdx.x == 0 && threadIdx.x == 0) offsets[N] = E;
}

// src node ids fit in uint16 (N < 65536).
// Grid-stride, 8 edges/thread/round: all 4 vector loads issued before the 8
// independent atomic+store pairs (raise MLP on ~500ns atomic round-trips).
#define SCAT_BLOCKS 256
__global__ __launch_bounds__(256) void scatter_edges(
    const int* __restrict__ dst, const int* __restrict__ src,
    int* __restrict__ cursor, unsigned short* __restrict__ ssorted, int E)
{
    const int t = blockIdx.x * 256 + threadIdx.x;
    const int nt = SCAT_BLOCKS * 256;
    const int ne4 = E >> 2;
    const intx4* d4 = (const intx4*)dst;
    const intx4* s4 = (const intx4*)src;
    int i = t;
    for (; i + nt < ne4; i += 2 * nt) {
        intx4 d0 = __builtin_nontemporal_load(d4 + i);
        intx4 s0 = __builtin_nontemporal_load(s4 + i);
        intx4 d1 = __builtin_nontemporal_load(d4 + i + nt);
        intx4 s1 = __builtin_nontemporal_load(s4 + i + nt);
        ssorted[atomicAdd(&cursor[d0.x], 1)] = (unsigned short)s0.x;
        ssorted[atomicAdd(&cursor[d0.y], 1)] = (unsigned short)s0.y;
        ssorted[atomicAdd(&cursor[d0.z], 1)] = (unsigned short)s0.z;
        ssorted[atomicAdd(&cursor[d0.w], 1)] = (unsigned short)s0.w;
        ssorted[atomicAdd(&cursor[d1.x], 1)] = (unsigned short)s1.x;
        ssorted[atomicAdd(&cursor[d1.y], 1)] = (unsigned short)s1.y;
        ssorted[atomicAdd(&cursor[d1.z], 1)] = (unsigned short)s1.z;
        ssorted[atomicAdd(&cursor[d1.w], 1)] = (unsigned short)s1.w;
    }
    for (; i < ne4; i += nt) {
        intx4 d = __builtin_nontemporal_load(d4 + i);
        intx4 s = __builtin_nontemporal_load(s4 + i);
        ssorted[atomicAdd(&cursor[d.x], 1)] = (unsigned short)s.x;
        ssorted[atomicAdd(&cursor[d.y], 1)] = (unsigned short)s.y;
        ssorted[atomicAdd(&cursor[d.z], 1)] = (unsigned short)s.z;
        ssorted[atomicAdd(&cursor[d.w], 1)] = (unsigned short)s.w;
    }
    if (t == 0) {
        for (int e = ne4 * 4; e < E; e++)
            ssorted[atomicAdd(&cursor[dst[e]], 1)] = (unsigned short)src[e];
    }
}

// ---- fused score + segment-softmax + aggregation (proven unroll-2) ----
// At the memory-system roofline: gathers E x 1KB = 800MB of KV rows in ~119us
// = ~6.7 TB/s effective. n0/n1: 4-way sub-launch split (instrumentation).
__global__ __launch_bounds__(256) void edge_agg(
    const unsigned short* __restrict__ Qb, const unsigned short* __restrict__ KV,
    const int* __restrict__ offsets, const unsigned short* __restrict__ ssorted,
    float* __restrict__ out, int n0, int n1)
{
    const int wave = threadIdx.x >> 6;
    const int lane = threadIdx.x & 63;
    const int half = lane >> 5;
    const int hl = lane & 31;
    const int n = n0 + blockIdx.x * 4 + wave;
    if (n >= n1) return;

    float q[8];
    {
        ushortx8 qu = __builtin_nontemporal_load((const ushortx8*)(Qb + (size_t)n * 256 + hl * 8));
#pragma unroll
        for (int j = 0; j < 8; j++) q[j] = bf2f(qu[j]);
    }

    float acc[8] = {};
    float z = 0.f;
    const int beg = offsets[n], end = offsets[n + 1];
    const int len = end - beg;
    const int mid = beg + ((len + 1) >> 1);
    const float scale = 0.17677669529663687f;  // 1/sqrt(32)

    int i = half ? mid : beg;
    const int i1 = half ? end : mid;

    for (; i + 1 < i1; i += 2) {
        int s0 = __builtin_nontemporal_load(ssorted + i);
        int s1 = __builtin_nontemporal_load(ssorted + i + 1);
        const unsigned short* p0 = KV + (size_t)s0 * 512 + hl * 8;
        const unsigned short* p1 = KV + (size_t)s1 * 512 + hl * 8;
        ushortx8 k0 = *(const ushortx8*)p0;        ushortx8 v0 = *(const ushortx8*)(p0 + 256);
        ushortx8 k1 = *(const ushortx8*)p1;        ushortx8 v1 = *(const ushortx8*)(p1 + 256);

        float d0 = 0.f, d1 = 0.f;
#pragma unroll
        for (int j = 0; j < 8; j++) {
            d0 = fmaf(bf2f(k0[j]), q[j], d0);
            d1 = fmaf(bf2f(k1[j]), q[j], d1);
        }
        d0 += __shfl_xor(d0, 1); d0 += __shfl_xor(d0, 2);
        d1 += __shfl_xor(d1, 1); d1 += __shfl_xor(d1, 2);
        float e0 = __expf(fminf(5.f, fmaxf(-5.f, d0 * scale)));
        float e1 = __expf(fminf(5.f, fmaxf(-5.f, d1 * scale)));
        z += e0 + e1;
#pragma unroll
        for (int j = 0; j < 8; j++) {
            acc[j] = fmaf(e0, bf2f(v0[j]), acc[j]);
            acc[j] = fmaf(e1, bf2f(v1[j]), acc[j]);
        }
    }
    for (; i < i1; i++) {
        int s = __builtin_nontemporal_load(ssorted + i);
        const unsigned short* p = KV + (size_t)s * 512 + hl * 8;
        ushortx8 k8 = *(const ushortx8*)p;
        ushortx8 v8 = *(const ushortx8*)(p + 256);
        float d = 0.f;
#pragma unroll
        for (int j = 0; j < 8; j++) d = fmaf(bf2f(k8[j]), q[j], d);
        d += __shfl_xor(d, 1); d += __shfl_xor(d, 2);
        float sc = __expf(fminf(5.f, fmaxf(-5.f, d * scale)));
        z += sc;
#pragma unroll
        for (int j = 0; j < 8; j++) acc[j] = fmaf(sc, bf2f(v8[j]), acc[j]);
    }

    z += __shfl_xor(z, 32);
#pragma unroll
    for (int j = 0; j < 8; j++) acc[j] += __shfl_xor(acc[j], 32);

    if (half == 0) {
        float inv = (z > 0.f) ? 1.f / z : 0.f;
        floatx4 o0, o1;
        o0[0] = acc[0] * inv; o0[1] = acc[1] * inv; o0[2] = acc[2] * inv; o0[3] = acc[3] * inv;
        o1[0] = acc[4] * inv; o1[1] = acc[5] * inv; o1[2] = acc[6] * inv; o1[3] = acc[7] * inv;
        floatx4* op = (floatx4*)(out + (size_t)n * 256 + hl * 8);
        __builtin_nontemporal_store(o0, op);
        __builtin_nontemporal_store(o1, op + 1);
    }
}

extern "C" void kernel_launch(void* const* d_in, const int* in_sizes, int n_in,
                              void* d_out, int out_size, void* d_ws, size_t ws_size,
                              hipStream_t stream) {
    const float* h  = (const float*)d_in[0];
    const float* Wq = (const float*)d_in[1];
    const float* bq = (const float*)d_in[2];
    const float* Wk = (const float*)d_in[3];
    const float* bk = (const float*)d_in[4];
    const float* Wv = (const float*)d_in[5];
    const float* bv = (const float*)d_in[6];
    const int*   src = (const int*)d_in[7];
    const int*   dst = (const int*)d_in[8];
    float* out = (float*)d_out;

    const int N = in_sizes[0] / 256;
    const int E = in_sizes[7];

    size_t off = 0;
    auto alloc = [&](size_t bytes) {
        void* p = (char*)d_ws + off;
        off += (bytes + 255) & ~(size_t)255;
        return p;
    };
    unsigned short* Qb = (unsigned short*)alloc((size_t)N * 256 * 2);
    unsigned short* KV = (unsigned short*)alloc((size_t)N * 512 * 2);
    unsigned short* hb = (unsigned short*)alloc((size_t)N * 256 * 2);
    unsigned short* Wb = (unsigned short*)alloc((size_t)768 * 256 * 2);
    int* deg      = (int*)alloc((size_t)N * 4);
    int* offsets  = (int*)alloc((size_t)(N + 1) * 4);
    int* cursor   = (int*)alloc((size_t)N * 4);
    int* partials = (int*)alloc(1024 * 4);
    unsigned short* ssorted = (unsigned short*)alloc((size_t)E * 2);

    // 0) fused prep: cvt h, cvt W, degree count (memset must precede atomics)
    hipMemsetAsync(deg, 0, (size_t)N * 4, stream);
    int n4h = (N * 256) / 4;
    int n4w = (256 * 256) / 4;
    prep<<<PREP_BH + 3 * PREP_BW + PREP_BD, 256, 0, stream>>>(
        h, hb, Wq, Wk, Wv, Wb, dst, deg, n4h, n4w, E);

    // 1) QKV projections (bf16 MFMA, BK=64, XCD-swizzled 1D grid)
    int nb6 = ((N + 127) / 128) * 6;
    qkv_gemm_mfma<<<nb6, 256, 0, stream>>>(hb, Wb, bq, bk, bv, Qb, KV, N);

    // 2) CSR scan + scatter (scan_phase2 folded into phase3's wave reduce)
    int nscan = (N + SCAN_CHUNK - 1) / SCAN_CHUNK;
    scan_phase1<<<nscan, 256, 0, stream>>>(deg, partials, N);
    scan_phase3<<<nscan, 256, 0, stream>>>(deg, partials, offsets, cursor, N, E, nscan);
    scatter_edges<<<SCAT_BLOCKS, 256, 0, stream>>>(dst, src, cursor, ssorted, E);

    // 3) fused score/softmax/aggregate — 4 sub-launches (instrumentation split)
    int q4 = (N + 3) / 4;
    for (int c = 0; c < 4; c++) {
        int lo = c * q4;
        if (lo >= N) break;
        int cnt = (N - lo < q4) ? (N - lo) : q4;
        edge_agg<<<(cnt + 3) / 4, 256, 0, stream>>>(Qb, KV, offsets, ssorted, out, lo, lo + cnt);
    }
}

// Round 6
// 336.152 us; speedup vs baseline: 1.0945x; 1.0945x over previous
//
#include <hip/hip_runtime.h>
#include <hip/hip_bf16.h>

// N=50000 nodes, IN=256, H=8 heads, D=32, HD=256, E=800000 edges (from in_sizes).

typedef __attribute__((ext_vector_type(8))) short short8;
typedef __attribute__((ext_vector_type(8))) unsigned short ushortx8;
typedef __attribute__((ext_vector_type(4))) unsigned short ushortx4;
typedef __attribute__((ext_vector_type(4))) float floatx4;
typedef __attribute__((ext_vector_type(4))) int intx4;

__device__ __forceinline__ void g2l16(const void* g, void* l) {
    __builtin_amdgcn_global_load_lds(
        (const __attribute__((address_space(1))) unsigned int*)g,
        (__attribute__((address_space(3))) unsigned int*)l, 16, 0, 0);
}

__device__ __forceinline__ float bf2f(unsigned short u) {
    union { unsigned int i; float f; } c; c.i = ((unsigned int)u) << 16; return c.f;
}
__device__ __forceinline__ unsigned short f2bf(float f) {
    __hip_bfloat16 b = __float2bfloat16(f);
    return *reinterpret_cast<unsigned short*>(&b);
}

__device__ __forceinline__ ushortx4 cvt4(floatx4 f) {
    ushortx4 u;
    u.x = f2bf(f.x); u.y = f2bf(f.y); u.z = f2bf(f.z); u.w = f2bf(f.w);
    return u;
}

// ---- K1: h->bf16, W->bf16, degree count (block-role fused) ----
// The deg histogram's 800K device-scope atomics (~45us tail, fabric-serialized)
// overlap the streaming cvt work. h/W sections are streaming-BW bound.
#define PREP_BH 1563
#define PREP_BW 16
#define PREP_BD 256

__global__ __launch_bounds__(256) void prep(
    const float* __restrict__ h, unsigned short* __restrict__ hb,
    const float* __restrict__ Wq, const float* __restrict__ Wk, const float* __restrict__ Wv,
    unsigned short* __restrict__ Wb,
    const int* __restrict__ dst, int* __restrict__ deg,
    int n4h, int n4w, int E)
{
    const int bid = blockIdx.x;
    const int tid = threadIdx.x;
    if (bid < PREP_BH) {
        const int stride = PREP_BH * 256;
        const floatx4* hs = (const floatx4*)h;
        ushortx4* hd = (ushortx4*)hb;
        int i = bid * 256 + tid;
        for (; i + 7 * stride < n4h; i += 8 * stride) {
            floatx4 f0 = __builtin_nontemporal_load(hs + i);
            floatx4 f1 = __builtin_nontemporal_load(hs + i + stride);
            floatx4 f2 = __builtin_nontemporal_load(hs + i + 2 * stride);
            floatx4 f3 = __builtin_nontemporal_load(hs + i + 3 * stride);
            floatx4 f4 = __builtin_nontemporal_load(hs + i + 4 * stride);
            floatx4 f5 = __builtin_nontemporal_load(hs + i + 5 * stride);
            floatx4 f6 = __builtin_nontemporal_load(hs + i + 6 * stride);
            floatx4 f7 = __builtin_nontemporal_load(hs + i + 7 * stride);
            hd[i] = cvt4(f0);
            hd[i + stride] = cvt4(f1);
            hd[i + 2 * stride] = cvt4(f2);
            hd[i + 3 * stride] = cvt4(f3);
            hd[i + 4 * stride] = cvt4(f4);
            hd[i + 5 * stride] = cvt4(f5);
            hd[i + 6 * stride] = cvt4(f6);
            hd[i + 7 * stride] = cvt4(f7);
        }
        for (; i < n4h; i += stride) {
            floatx4 f = __builtin_nontemporal_load(hs + i);
            hd[i] = cvt4(f);
        }
    } else if (bid < PREP_BH + 3 * PREP_BW) {
        int b2 = bid - PREP_BH;
        int mat = b2 / PREP_BW;
        const floatx4* ws = (const floatx4*)((mat == 0) ? Wq : (mat == 1) ? Wk : Wv);
        ushortx4* wd = (ushortx4*)(Wb + (size_t)mat * 65536);
        const int stride = PREP_BW * 256;
        int i = (b2 % PREP_BW) * 256 + tid;
        for (; i + 3 * stride < n4w; i += 4 * stride) {
            floatx4 f0 = __builtin_nontemporal_load(ws + i);
            floatx4 f1 = __builtin_nontemporal_load(ws + i + stride);
            floatx4 f2 = __builtin_nontemporal_load(ws + i + 2 * stride);
            floatx4 f3 = __builtin_nontemporal_load(ws + i + 3 * stride);
            wd[i] = cvt4(f0);
            wd[i + stride] = cvt4(f1);
            wd[i + 2 * stride] = cvt4(f2);
            wd[i + 3 * stride] = cvt4(f3);
        }
        for (; i < n4w; i += stride) {
            floatx4 f = __builtin_nontemporal_load(ws + i);
            wd[i] = cvt4(f);
        }
    } else {
        int b3 = bid - PREP_BH - 3 * PREP_BW;
        const int stride = PREP_BD * 256;
        const int ne4 = E >> 2;
        const intx4* ds = (const intx4*)dst;
        int i = b3 * 256 + tid;
        for (; i + stride < ne4; i += 2 * stride) {
            intx4 d0 = __builtin_nontemporal_load(ds + i);
            intx4 d1 = __builtin_nontemporal_load(ds + i + stride);
            atomicAdd(&deg[d0.x], 1); atomicAdd(&deg[d0.y], 1);
            atomicAdd(&deg[d0.z], 1); atomicAdd(&deg[d0.w], 1);
            atomicAdd(&deg[d1.x], 1); atomicAdd(&deg[d1.y], 1);
            atomicAdd(&deg[d1.z], 1); atomicAdd(&deg[d1.w], 1);
        }
        for (; i < ne4; i += stride) {
            intx4 d = __builtin_nontemporal_load(ds + i);
            atomicAdd(&deg[d.x], 1); atomicAdd(&deg[d.y], 1);
            atomicAdd(&deg[d.z], 1); atomicAdd(&deg[d.w], 1);
        }
        if (b3 == 0 && tid == 0) {
            for (int e = ne4 * 4; e < E; e++) atomicAdd(&deg[dst[e]], 1);
        }
    }
}

#define SCAN_CHUNK 2048  // 256 threads x 8

__global__ void scan_phase1(const int* __restrict__ deg, int* __restrict__ partials, int N) {
    __shared__ int sdata[256];
    int base = blockIdx.x * SCAN_CHUNK;
    int sum = 0;
#pragma unroll
    for (int i = 0; i < 8; i++) {
        int idx = base + threadIdx.x + i * 256;
        if (idx < N) sum += deg[idx];
    }
    sdata[threadIdx.x] = sum;
    __syncthreads();
    for (int s = 128; s > 0; s >>= 1) {
        if (threadIdx.x < (unsigned)s) sdata[threadIdx.x] += sdata[threadIdx.x + s];
        __syncthreads();
    }
    if (threadIdx.x == 0) partials[blockIdx.x] = sdata[0];
}

// scan_phase3 with inlined cross-block prefix (wave-reduce of raw partials; nb<=64)
__global__ void scan_phase3(const int* __restrict__ deg, const int* __restrict__ partials,
                            int* __restrict__ offsets, int* __restrict__ cursor,
                            int N, int E, int nb) {
    __shared__ int sdata[256];
    __shared__ int sbase;
    if (threadIdx.x < 64) {
        int v = ((int)threadIdx.x < nb && (int)threadIdx.x < (int)blockIdx.x)
                    ? partials[threadIdx.x] : 0;
#pragma unroll
        for (int s = 1; s < 64; s <<= 1) v += __shfl_xor(v, s);
        if (threadIdx.x == 0) sbase = v;
    }
    int base = blockIdx.x * SCAN_CHUNK;
    int vals[8];
    int sum = 0;
#pragma unroll
    for (int i = 0; i < 8; i++) {
        int idx = base + threadIdx.x * 8 + i;
        vals[i] = (idx < N) ? deg[idx] : 0;
        sum += vals[i];
    }
    sdata[threadIdx.x] = sum;
    __syncthreads();
    for (int s = 1; s < 256; s <<= 1) {
        int v = sdata[threadIdx.x];
        int add = (threadIdx.x >= (unsigned)s) ? sdata[threadIdx.x - s] : 0;
        __syncthreads();
        sdata[threadIdx.x] = v + add;
        __syncthreads();
    }
    int excl = (threadIdx.x == 0) ? 0 : sdata[threadIdx.x - 1];
    int run = sbase + excl;
#pragma unroll
    for (int i = 0; i < 8; i++) {
        int idx = base + threadIdx.x * 8 + i;
        if (idx < N) { offsets[idx] = run; cursor[idx] = run; }
        run += vals[i];
    }
    if (blockIdx.x == 0 && threadIdx.x == 0) offsets[N] = E;
}

// ---- K4: fused scatter + GEMM (independent work, one kernel for overlap) ----
// Blocks [0, SCAT_BLOCKS): edge scatter (800K device atomics, fabric-latency-
// bound). Blocks [SCAT_BLOCKS, ...): bf16 MFMA QKV projection (compute-bound).
// The scatter's atomic latency hides under GEMM execution: max() not sum().
#define SCAT_BLOCKS 256

__global__ __launch_bounds__(256) void gemm_scatter(
    const unsigned short* __restrict__ hb, const unsigned short* __restrict__ Wb,
    const float* __restrict__ bq, const float* __restrict__ bk, const float* __restrict__ bv,
    unsigned short* __restrict__ Qb, unsigned short* __restrict__ KV, int N,
    const int* __restrict__ dst, const int* __restrict__ src,
    int* __restrict__ cursor, unsigned short* __restrict__ ssorted, int E, int nb6)
{
    __shared__ unsigned short Ast[2][128 * 32];
    __shared__ unsigned short Bst[2][128 * 32];

    const int bid = blockIdx.x;
    const int tid = threadIdx.x;

    if (bid < SCAT_BLOCKS) {
        // ---- scatter role (grid-stride, 8 atomic chains in flight/thread) ----
        const int t = bid * 256 + tid;
        const int nt = SCAT_BLOCKS * 256;
        const int ne4 = E >> 2;
        const intx4* d4 = (const intx4*)dst;
        const intx4* s4 = (const intx4*)src;
        int i = t;
        for (; i + nt < ne4; i += 2 * nt) {
            intx4 d0 = __builtin_nontemporal_load(d4 + i);
            intx4 s0 = __builtin_nontemporal_load(s4 + i);
            intx4 d1 = __builtin_nontemporal_load(d4 + i + nt);
            intx4 s1 = __builtin_nontemporal_load(s4 + i + nt);
            ssorted[atomicAdd(&cursor[d0.x], 1)] = (unsigned short)s0.x;
            ssorted[atomicAdd(&cursor[d0.y], 1)] = (unsigned short)s0.y;
            ssorted[atomicAdd(&cursor[d0.z], 1)] = (unsigned short)s0.z;
            ssorted[atomicAdd(&cursor[d0.w], 1)] = (unsigned short)s0.w;
            ssorted[atomicAdd(&cursor[d1.x], 1)] = (unsigned short)s1.x;
            ssorted[atomicAdd(&cursor[d1.y], 1)] = (unsigned short)s1.y;
            ssorted[atomicAdd(&cursor[d1.z], 1)] = (unsigned short)s1.z;
            ssorted[atomicAdd(&cursor[d1.w], 1)] = (unsigned short)s1.w;
        }
        for (; i < ne4; i += nt) {
            intx4 d = __builtin_nontemporal_load(d4 + i);
            intx4 s = __builtin_nontemporal_load(s4 + i);
            ssorted[atomicAdd(&cursor[d.x], 1)] = (unsigned short)s.x;
            ssorted[atomicAdd(&cursor[d.y], 1)] = (unsigned short)s.y;
            ssorted[atomicAdd(&cursor[d.z], 1)] = (unsigned short)s.z;
            ssorted[atomicAdd(&cursor[d.w], 1)] = (unsigned short)s.w;
        }
        if (t == 0) {
            for (int e = ne4 * 4; e < E; e++)
                ssorted[atomicAdd(&cursor[dst[e]], 1)] = (unsigned short)src[e];
        }
        return;
    }

    // ---- GEMM role (proven BK=64 loop; XCD swizzle over the GEMM sub-grid) ----
    const int wave = tid >> 6;
    const int lane = tid & 63;
    const int m = lane & 15;
    const int q = lane >> 4;
    const int wr = wave >> 1, wc = wave & 1;

    const int orig = bid - SCAT_BLOCKS;
    const int q8 = nb6 >> 3, r8 = nb6 & 7;
    const int xcd = orig & 7;
    const int wgid = (xcd < r8 ? xcd * (q8 + 1) : r8 * (q8 + 1) + (xcd - r8) * q8)
                     + (orig >> 3);
    const int bx = wgid / 6;   // row tile
    const int by = wgid % 6;   // mat/col-half

    const int mbase = bx * 128;
    const int mat = by >> 1;                 // 0:Q 1:K 2:V
    const int colbase = (by & 1) * 128;
    const int wrow0 = by * 128;

    const float* bias = (mat == 0) ? bq : (mat == 1) ? bk : bv;

    floatx4 acc[4][4] = {};

    for (int kk = 0; kk < 256; kk += 64) {
#pragma unroll
        for (int c = 0; c < 2; c++) {
#pragma unroll
            for (int t = 0; t < 2; t++) {
                int f = t * 256 + tid;
                int row = f >> 2, kc = f & 3;
                int grow = mbase + row; if (grow > N - 1) grow = N - 1;
                g2l16(hb + (size_t)grow * 256 + kk + c * 32 + kc * 8,
                      Ast[c] + (size_t)(t * 256 + wave * 64) * 8);
            }
#pragma unroll
            for (int t = 0; t < 2; t++) {
                int f = t * 256 + tid;
                int row = f >> 2, kc = f & 3;
                g2l16(Wb + (size_t)(wrow0 + row) * 256 + kk + c * 32 + kc * 8,
                      Bst[c] + (size_t)(t * 256 + wave * 64) * 8);
            }
        }
        __syncthreads();

#pragma unroll
        for (int c = 0; c < 2; c++) {
            short8 a[4], b[4];
#pragma unroll
            for (int i = 0; i < 4; i++) {
                int r = wr * 64 + i * 16 + m;
                a[i] = *(const short8*)&Ast[c][r * 32 + q * 8];
            }
#pragma unroll
            for (int j = 0; j < 4; j++) {
                int cc = wc * 64 + j * 16 + m;
                b[j] = *(const short8*)&Bst[c][cc * 32 + q * 8];
            }
#pragma unroll
            for (int i = 0; i < 4; i++)
#pragma unroll
                for (int j = 0; j < 4; j++)
                    acc[i][j] = __builtin_amdgcn_mfma_f32_16x16x32_bf16(a[i], b[j], acc[i][j], 0, 0, 0);
        }
        __syncthreads();
    }

    float bvj[4];
#pragma unroll
    for (int j = 0; j < 4; j++) bvj[j] = bias[colbase + wc * 64 + j * 16 + m];

    const int col0 = colbase + wc * 64 + m;
    // C/D layout: col = lane&15, row = (lane>>4)*4 + reg
#pragma unroll
    for (int i = 0; i < 4; i++) {
#pragma unroll
        for (int r = 0; r < 4; r++) {
            int grow = mbase + wr * 64 + i * 16 + q * 4 + r;
            if (grow < N) {
                if (mat == 0) {
                    unsigned short* op = Qb + (size_t)grow * 256 + col0;
#pragma unroll
                    for (int j = 0; j < 4; j++)
                        __builtin_nontemporal_store(f2bf(acc[i][j][r] + bvj[j]), op + j * 16);
                } else {
                    unsigned short* op = KV + (size_t)grow * 512 + ((mat == 2) ? 256 : 0) + col0;
#pragma unroll
                    for (int j = 0; j < 4; j++)
                        op[j * 16] = f2bf(acc[i][j][r] + bvj[j]);
                }
            }
        }
    }
}

// ---- fused score + segment-softmax + aggregation (proven unroll-2) ----
// At the memory-system roofline: gathers E x 1KB = 800MB of KV rows in ~118us
// = ~6.7 TB/s effective (L2/LLC + HBM mix).
__global__ __launch_bounds__(256) void edge_agg(
    const unsigned short* __restrict__ Qb, const unsigned short* __restrict__ KV,
    const int* __restrict__ offsets, const unsigned short* __restrict__ ssorted,
    float* __restrict__ out, int N)
{
    const int wave = threadIdx.x >> 6;
    const int lane = threadIdx.x & 63;
    const int half = lane >> 5;
    const int hl = lane & 31;
    const int n = blockIdx.x * 4 + wave;
    if (n >= N) return;

    float q[8];
    {
        ushortx8 qu = __builtin_nontemporal_load((const ushortx8*)(Qb + (size_t)n * 256 + hl * 8));
#pragma unroll
        for (int j = 0; j < 8; j++) q[j] = bf2f(qu[j]);
    }

    float acc[8] = {};
    float z = 0.f;
    const int beg = offsets[n], end = offsets[n + 1];
    const int len = end - beg;
    const int mid = beg + ((len + 1) >> 1);
    const float scale = 0.17677669529663687f;  // 1/sqrt(32)

    int i = half ? mid : beg;
    const int i1 = half ? end : mid;

    for (; i + 1 < i1; i += 2) {
        int s0 = __builtin_nontemporal_load(ssorted + i);
        int s1 = __builtin_nontemporal_load(ssorted + i + 1);
        const unsigned short* p0 = KV + (size_t)s0 * 512 + hl * 8;
        const unsigned short* p1 = KV + (size_t)s1 * 512 + hl * 8;
        ushortx8 k0 = *(const ushortx8*)p0;        ushortx8 v0 = *(const ushortx8*)(p0 + 256);
        ushortx8 k1 = *(const ushortx8*)p1;        ushortx8 v1 = *(const ushortx8*)(p1 + 256);

        float d0 = 0.f, d1 = 0.f;
#pragma unroll
        for (int j = 0; j < 8; j++) {
            d0 = fmaf(bf2f(k0[j]), q[j], d0);
            d1 = fmaf(bf2f(k1[j]), q[j], d1);
        }
        d0 += __shfl_xor(d0, 1); d0 += __shfl_xor(d0, 2);
        d1 += __shfl_xor(d1, 1); d1 += __shfl_xor(d1, 2);
        float e0 = __expf(fminf(5.f, fmaxf(-5.f, d0 * scale)));
        float e1 = __expf(fminf(5.f, fmaxf(-5.f, d1 * scale)));
        z += e0 + e1;
#pragma unroll
        for (int j = 0; j < 8; j++) {
            acc[j] = fmaf(e0, bf2f(v0[j]), acc[j]);
            acc[j] = fmaf(e1, bf2f(v1[j]), acc[j]);
        }
    }
    for (; i < i1; i++) {
        int s = __builtin_nontemporal_load(ssorted + i);
        const unsigned short* p = KV + (size_t)s * 512 + hl * 8;
        ushortx8 k8 = *(const ushortx8*)p;
        ushortx8 v8 = *(const ushortx8*)(p + 256);
        float d = 0.f;
#pragma unroll
        for (int j = 0; j < 8; j++) d = fmaf(bf2f(k8[j]), q[j], d);
        d += __shfl_xor(d, 1); d += __shfl_xor(d, 2);
        float sc = __expf(fminf(5.f, fmaxf(-5.f, d * scale)));
        z += sc;
#pragma unroll
        for (int j = 0; j < 8; j++) acc[j] = fmaf(sc, bf2f(v8[j]), acc[j]);
    }

    z += __shfl_xor(z, 32);
#pragma unroll
    for (int j = 0; j < 8; j++) acc[j] += __shfl_xor(acc[j], 32);

    if (half == 0) {
        float inv = (z > 0.f) ? 1.f / z : 0.f;
        floatx4 o0, o1;
        o0[0] = acc[0] * inv; o0[1] = acc[1] * inv; o0[2] = acc[2] * inv; o0[3] = acc[3] * inv;
        o1[0] = acc[4] * inv; o1[1] = acc[5] * inv; o1[2] = acc[6] * inv; o1[3] = acc[7] * inv;
        floatx4* op = (floatx4*)(out + (size_t)n * 256 + hl * 8);
        __builtin_nontemporal_store(o0, op);
        __builtin_nontemporal_store(o1, op + 1);
    }
}

extern "C" void kernel_launch(void* const* d_in, const int* in_sizes, int n_in,
                              void* d_out, int out_size, void* d_ws, size_t ws_size,
                              hipStream_t stream) {
    const float* h  = (const float*)d_in[0];
    const float* Wq = (const float*)d_in[1];
    const float* bq = (const float*)d_in[2];
    const float* Wk = (const float*)d_in[3];
    const float* bk = (const float*)d_in[4];
    const float* Wv = (const float*)d_in[5];
    const float* bv = (const float*)d_in[6];
    const int*   src = (const int*)d_in[7];
    const int*   dst = (const int*)d_in[8];
    float* out = (float*)d_out;

    const int N = in_sizes[0] / 256;
    const int E = in_sizes[7];

    size_t off = 0;
    auto alloc = [&](size_t bytes) {
        void* p = (char*)d_ws + off;
        off += (bytes + 255) & ~(size_t)255;
        return p;
    };
    unsigned short* Qb = (unsigned short*)alloc((size_t)N * 256 * 2);
    unsigned short* KV = (unsigned short*)alloc((size_t)N * 512 * 2);
    unsigned short* hb = (unsigned short*)alloc((size_t)N * 256 * 2);
    unsigned short* Wb = (unsigned short*)alloc((size_t)768 * 256 * 2);
    int* deg      = (int*)alloc((size_t)N * 4);
    int* offsets  = (int*)alloc((size_t)(N + 1) * 4);
    int* cursor   = (int*)alloc((size_t)N * 4);
    int* partials = (int*)alloc(1024 * 4);
    unsigned short* ssorted = (unsigned short*)alloc((size_t)E * 2);

    // 0) K1: cvt h, cvt W, degree count (memset must precede atomics)
    hipMemsetAsync(deg, 0, (size_t)N * 4, stream);
    int n4h = (N * 256) / 4;
    int n4w = (256 * 256) / 4;
    prep<<<PREP_BH + 3 * PREP_BW + PREP_BD, 256, 0, stream>>>(
        h, hb, Wq, Wk, Wv, Wb, dst, deg, n4h, n4w, E);

    // 1) CSR scan (scan_phase2 folded into phase3's wave reduce)
    int nscan = (N + SCAN_CHUNK - 1) / SCAN_CHUNK;
    scan_phase1<<<nscan, 256, 0, stream>>>(deg, partials, N);
    scan_phase3<<<nscan, 256, 0, stream>>>(deg, partials, offsets, cursor, N, E, nscan);

    // 2) K4: fused scatter (atomic-latency-bound) + QKV GEMM (compute-bound).
    //    Independent work: scatter needs cursor (done), GEMM needs hb/Wb (done).
    int nb6 = ((N + 127) / 128) * 6;
    gemm_scatter<<<SCAT_BLOCKS + nb6, 256, 0, stream>>>(
        hb, Wb, bq, bk, bv, Qb, KV, N, dst, src, cursor, ssorted, E, nb6);

    // 3) fused score/softmax/aggregate
    int ablocks = (N + 3) / 4;
    edge_agg<<<ablocks, 256, 0, stream>>>(Qb, KV, offsets, ssorted, out, N);
}